// Round 1
// baseline (5014.240 us; speedup 1.0000x reference)
//
#include <hip/hip_runtime.h>
#include <cstdint>
#include <cstddef>

// ---------------------------------------------------------------------------
// Problem constants (from reference setup_inputs)
// ---------------------------------------------------------------------------
#define NC    10000      // cells
#define EE    320000     // edges per order
#define HID   256        // hidden
#define KHOP  10         // propagation hops
#define D_RNA 2000
#define D_ATAC 5000

static inline int cdiv(int a, int b) { return (a + b - 1) / b; }

// ---------------------------------------------------------------------------
// fW softmax: 4 rows (rna o0, rna o1, atac o0, atac o1) x 11
// ---------------------------------------------------------------------------
__global__ void fw_softmax_kernel(const float* __restrict__ fW_rna,
                                  const float* __restrict__ fW_atac,
                                  float* __restrict__ fw_soft) {
    int t = threadIdx.x;
    if (t < 4) {
        const float* src = (t < 2) ? (fW_rna + t * (KHOP + 1))
                                   : (fW_atac + (t - 2) * (KHOP + 1));
        float mx = -1e30f;
        for (int k = 0; k <= KHOP; k++) mx = fmaxf(mx, src[k]);
        float e[KHOP + 1];
        float s = 0.f;
        for (int k = 0; k <= KHOP; k++) { e[k] = expf(src[k] - mx); s += e[k]; }
        float inv = 1.f / s;
        for (int k = 0; k <= KHOP; k++) fw_soft[t * (KHOP + 1) + k] = e[k] * inv;
    }
}

// ---------------------------------------------------------------------------
// CSR build: histogram -> scan -> scatter
// ---------------------------------------------------------------------------
__global__ void hist_kernel(const int* __restrict__ row, int e_count,
                            int* __restrict__ counts) {
    int e = blockIdx.x * blockDim.x + threadIdx.x;
    if (e < e_count) atomicAdd(&counts[row[e]], 1);
}

__global__ __launch_bounds__(1024) void scan_kernel(const int* __restrict__ counts,
                                                    int* __restrict__ row_start,
                                                    int* __restrict__ cursor,
                                                    int n) {
    __shared__ int part[1024];
    int t = threadIdx.x;
    const int PER = (n + 1023) / 1024;
    int base = t * PER;
    int s = 0;
    for (int i = 0; i < PER; i++) {
        int idx = base + i;
        if (idx < n) s += counts[idx];
    }
    part[t] = s;
    __syncthreads();
    for (int off = 1; off < 1024; off <<= 1) {
        int v = (t >= off) ? part[t - off] : 0;
        __syncthreads();
        part[t] += v;
        __syncthreads();
    }
    int run = (t == 0) ? 0 : part[t - 1];
    for (int i = 0; i < PER; i++) {
        int idx = base + i;
        if (idx < n) {
            row_start[idx] = run;
            cursor[idx] = run;
            run += counts[idx];
        }
    }
    if (t == 1023) row_start[n] = part[1023];
}

__global__ void scatter_kernel(const int* __restrict__ row,
                               const int* __restrict__ col,
                               const float* __restrict__ val, int e_count,
                               int* __restrict__ cursor,
                               int* __restrict__ col_s,
                               float* __restrict__ val_s) {
    int e = blockIdx.x * blockDim.x + threadIdx.x;
    if (e < e_count) {
        int p = atomicAdd(&cursor[row[e]], 1);
        col_s[p] = col[e];
        val_s[p] = val[e];
    }
}

// ---------------------------------------------------------------------------
// acc init: acc = fw[0] * h, writing into split (rna|atac) concat buffers
// h layout: [N, 512] with cols 0-255 = rna, 256-511 = atac (one order)
// Zrna/Zatac layout: [N, 512] with cols order*256 .. order*256+255
// ---------------------------------------------------------------------------
__global__ __launch_bounds__(512) void init_acc_kernel(const float* __restrict__ h,
                                                       float* __restrict__ zrna,
                                                       float* __restrict__ zatac,
                                                       const float* __restrict__ fw_soft,
                                                       int order) {
    int n = blockIdx.x;
    int c = threadIdx.x;
    float v = h[(size_t)n * 512 + c];
    if (c < 256) {
        float w = fw_soft[order * (KHOP + 1) + 0];
        zrna[(size_t)n * 512 + order * 256 + c] = w * v;
    } else {
        float w = fw_soft[(2 + order) * (KHOP + 1) + 0];
        zatac[(size_t)n * 512 + order * 256 + (c - 256)] = w * v;
    }
}

// ---------------------------------------------------------------------------
// CSR SpMM over [N,512] fused with acc += w_k * xk
// one block (512 threads) per row
// ---------------------------------------------------------------------------
__global__ __launch_bounds__(512) void spmm_acc_kernel(
    const int* __restrict__ row_start,
    const int* __restrict__ col_s,
    const float* __restrict__ val_s,
    const float* __restrict__ x,
    float* __restrict__ y,
    float* __restrict__ zrna,
    float* __restrict__ zatac,
    const float* __restrict__ fw_soft,
    int order, int k) {
    int n = blockIdx.x;
    int c = threadIdx.x;
    int s = row_start[n];
    int e = row_start[n + 1];
    float acc = 0.f;
    for (int i = s; i < e; i++) {
        int cc = col_s[i];
        float v = val_s[i];
        acc += v * x[(size_t)cc * 512 + c];
    }
    y[(size_t)n * 512 + c] = acc;
    if (c < 256) {
        float w = fw_soft[order * (KHOP + 1) + k];
        zrna[(size_t)n * 512 + order * 256 + c] += w * acc;
    } else {
        float w = fw_soft[(2 + order) * (KHOP + 1) + k];
        zatac[(size_t)n * 512 + order * 256 + (c - 256)] += w * acc;
    }
}

// ---------------------------------------------------------------------------
// Attention fusion: attn = [z_rna|z_atac] @ Wa + ba ; softmax ; z = w0*zr+w1*za
// one block (256 threads) per node
// ---------------------------------------------------------------------------
__global__ __launch_bounds__(256) void attention_kernel(
    const float* __restrict__ z_rna, const float* __restrict__ z_atac,
    const float* __restrict__ Wa, const float* __restrict__ ba,
    float* __restrict__ z, float* __restrict__ weight) {
    int n = blockIdx.x;
    int t = threadIdx.x;
    float zr = z_rna[(size_t)n * 256 + t];
    float za = z_atac[(size_t)n * 256 + t];
    float p0 = zr * Wa[t * 2 + 0] + za * Wa[(256 + t) * 2 + 0];
    float p1 = zr * Wa[t * 2 + 1] + za * Wa[(256 + t) * 2 + 1];
    for (int off = 32; off > 0; off >>= 1) {
        p0 += __shfl_down(p0, off);
        p1 += __shfl_down(p1, off);
    }
    __shared__ float red0[4], red1[4];
    __shared__ float w0s, w1s;
    int wave = t >> 6, lane = t & 63;
    if (lane == 0) { red0[wave] = p0; red1[wave] = p1; }
    __syncthreads();
    if (t == 0) {
        float a0 = red0[0] + red0[1] + red0[2] + red0[3] + ba[0];
        float a1 = red1[0] + red1[1] + red1[2] + red1[3] + ba[1];
        float m = fmaxf(a0, a1);
        float e0 = expf(a0 - m), e1 = expf(a1 - m);
        float inv = 1.f / (e0 + e1);
        w0s = e0 * inv; w1s = e1 * inv;
        weight[(size_t)n * 2 + 0] = w0s;
        weight[(size_t)n * 2 + 1] = w1s;
    }
    __syncthreads();
    z[(size_t)n * 256 + t] = w0s * zr + w1s * za;
}

// ---------------------------------------------------------------------------
// Tiled f32 GEMM: C[M,N] = A[M,K] @ B[K,N] + bias[N], optional relu.
// Requires: BM*BK == 1024, BK*BN == 1024, (BM/TM)*(BN/TN) == 256,
//           K % 4 == 0, N % 4 == 0, ldc/lda/ldb % 4 == 0 (float4 alignment).
// ---------------------------------------------------------------------------
template <int BM, int BN, int BK, int TM, int TN, bool RELU>
__global__ __launch_bounds__(256) void gemm_f32(
    const float* __restrict__ A, int lda,
    const float* __restrict__ B, int ldb,
    const float* __restrict__ bias,
    float* __restrict__ C, int ldc,
    int M, int N, int K) {
    constexpr int TX = BN / TN;
    constexpr int TY = BM / TM;
    static_assert(TX * TY == 256, "thread tile mismatch");
    static_assert(BM * BK == 1024 && BK * BN == 1024, "single-pass load");
    constexpr int LDA_S = BM + 4;
    constexpr int LDB_S = BN + 4;
    __shared__ __align__(16) float As[BK * LDA_S];
    __shared__ __align__(16) float Bs[BK * LDB_S];

    const int tid = threadIdx.x;
    const int tx = tid % TX;
    const int ty = tid / TX;
    const int m0 = blockIdx.y * BM;
    const int n0 = blockIdx.x * BN;

    constexpr int KV = BK / 4;   // float4s per A-tile row
    const int a_row = tid / KV;
    const int a_k = (tid % KV) * 4;
    constexpr int NV = BN / 4;
    const int b_row = tid / NV;  // k index in B tile
    const int b_col = (tid % NV) * 4;

    const int arow_g = m0 + a_row;
    const bool a_rowok = arow_g < M;

    float acc[TM][TN];
#pragma unroll
    for (int i = 0; i < TM; i++)
#pragma unroll
        for (int j = 0; j < TN; j++) acc[i][j] = 0.f;

    for (int kt = 0; kt < K; kt += BK) {
        float4 a4 = make_float4(0.f, 0.f, 0.f, 0.f);
        if (a_rowok && (kt + a_k) < K)
            a4 = *(const float4*)(A + (size_t)arow_g * lda + kt + a_k);
        float4 b4 = make_float4(0.f, 0.f, 0.f, 0.f);
        int bk_g = kt + b_row;
        int bn_g = n0 + b_col;
        if (bk_g < K && bn_g < N)
            b4 = *(const float4*)(B + (size_t)bk_g * ldb + bn_g);

        __syncthreads();
        As[(a_k + 0) * LDA_S + a_row] = a4.x;
        As[(a_k + 1) * LDA_S + a_row] = a4.y;
        As[(a_k + 2) * LDA_S + a_row] = a4.z;
        As[(a_k + 3) * LDA_S + a_row] = a4.w;
        *(float4*)(Bs + b_row * LDB_S + b_col) = b4;
        __syncthreads();

#pragma unroll
        for (int kk = 0; kk < BK; kk++) {
            float a[TM], b[TN];
#pragma unroll
            for (int i = 0; i < TM; i += 4)
                *(float4*)&a[i] = *(const float4*)&As[kk * LDA_S + ty * TM + i];
#pragma unroll
            for (int j = 0; j < TN; j += 4)
                *(float4*)&b[j] = *(const float4*)&Bs[kk * LDB_S + tx * TN + j];
#pragma unroll
            for (int i = 0; i < TM; i++)
#pragma unroll
                for (int j = 0; j < TN; j++) acc[i][j] += a[i] * b[j];
        }
    }

    // epilogue
    float bb[TN];
#pragma unroll
    for (int j = 0; j < TN; j++) {
        int n = n0 + tx * TN + j;
        bb[j] = (n < N) ? bias[n] : 0.f;
    }
#pragma unroll
    for (int i = 0; i < TM; i++) {
        int m = m0 + ty * TM + i;
        if (m >= M) continue;
#pragma unroll
        for (int j = 0; j < TN; j += 4) {
            int n = n0 + tx * TN + j;
            if (n >= N) continue;  // N % 4 == 0 -> whole float4 in bounds
            float4 v;
            v.x = acc[i][j + 0] + bb[j + 0];
            v.y = acc[i][j + 1] + bb[j + 1];
            v.z = acc[i][j + 2] + bb[j + 2];
            v.w = acc[i][j + 3] + bb[j + 3];
            if (RELU) {
                v.x = fmaxf(v.x, 0.f);
                v.y = fmaxf(v.y, 0.f);
                v.z = fmaxf(v.z, 0.f);
                v.w = fmaxf(v.w, 0.f);
            }
            *(float4*)(C + (size_t)m * ldc + n) = v;
        }
    }
}

// ---------------------------------------------------------------------------
// Host orchestration
// ---------------------------------------------------------------------------
extern "C" void kernel_launch(void* const* d_in, const int* in_sizes, int n_in,
                              void* d_out, int out_size, void* d_ws, size_t ws_size,
                              hipStream_t stream) {
    const float* X_rna   = (const float*)d_in[0];
    const float* X_atac  = (const float*)d_in[1];
    const int*   row_in[2] = {(const int*)d_in[2], (const int*)d_in[5]};
    const int*   col_in[2] = {(const int*)d_in[3], (const int*)d_in[6]};
    const float* val_in[2] = {(const float*)d_in[4], (const float*)d_in[7]};
    const float* Wi_rna  = (const float*)d_in[8];
    const float* bi_rna  = (const float*)d_in[9];
    const float* fW_rna  = (const float*)d_in[10];
    const float* Wo_rna  = (const float*)d_in[11];
    const float* bo_rna  = (const float*)d_in[12];
    const float* Wi_atac = (const float*)d_in[13];
    const float* bi_atac = (const float*)d_in[14];
    const float* fW_atac = (const float*)d_in[15];
    const float* Wo_atac = (const float*)d_in[16];
    const float* bo_atac = (const float*)d_in[17];
    const float* Wa      = (const float*)d_in[18];
    const float* ba      = (const float*)d_in[19];
    const float* Wd1_rna = (const float*)d_in[20];
    const float* bd1_rna = (const float*)d_in[21];
    const float* Wd2_rna = (const float*)d_in[22];
    const float* bd2_rna = (const float*)d_in[23];
    const float* Wd1_atac = (const float*)d_in[24];
    const float* bd1_atac = (const float*)d_in[25];
    const float* Wd2_atac = (const float*)d_in[26];
    const float* bd2_atac = (const float*)d_in[27];

    float* out = (float*)d_out;
    // output tuple layout (flat, return order)
    float* o_z        = out;                    // [N,256]
    float* o_z_rna    = out + 2560000;          // [N,256]
    float* o_z_atac   = out + 5120000;          // [N,256]
    float* o_weight   = out + 7680000;          // [N,2]
    float* o_rna_rec  = out + 7700000;          // [N,2000]
    float* o_atac_rec = out + 27700000;         // [N,5000]

    // scratch hosted inside the (not-yet-written) atac_rec output region:
    // all four buffers are dead before the final decoder GEMM writes atac_rec.
    float* xk_a  = o_atac_rec;                  // [N,512]
    float* xk_b  = o_atac_rec + 5120000;        // [N,512]
    float* Zrna  = o_atac_rec + 10240000;       // [N,512] concat input for Wo_rna
    float* Zatac = o_atac_rec + 15360000;       // [N,512] concat input for Wo_atac

    // ws scratch (~26 MB)
    char* w = (char*)d_ws;
    float* fw_soft = (float*)w;  w += 256;
    float* d1_rna  = (float*)w;  w += (size_t)NC * 256 * 4;   // 10.24 MB
    float* d1_atac = (float*)w;  w += (size_t)NC * 256 * 4;   // 10.24 MB
    int*   counts[2]; int* rstart[2]; int* cursor[2]; int* cols_s[2]; float* vals_s[2];
    for (int o = 0; o < 2; o++) {
        counts[o] = (int*)w;   w += 40960;
        rstart[o] = (int*)w;   w += 40960;
        cursor[o] = (int*)w;   w += 40960;
        cols_s[o] = (int*)w;   w += (size_t)EE * 4;
        vals_s[o] = (float*)w; w += (size_t)EE * 4;
    }

    // 1. fW softmax
    fw_softmax_kernel<<<1, 64, 0, stream>>>(fW_rna, fW_atac, fw_soft);

    // 2. CSR build for both edge orders
    for (int o = 0; o < 2; o++) {
        hipMemsetAsync(counts[o], 0, NC * sizeof(int), stream);
        hist_kernel<<<cdiv(EE, 256), 256, 0, stream>>>(row_in[o], EE, counts[o]);
        scan_kernel<<<1, 1024, 0, stream>>>(counts[o], rstart[o], cursor[o], NC);
        scatter_kernel<<<cdiv(EE, 256), 256, 0, stream>>>(
            row_in[o], col_in[o], val_in[o], EE, cursor[o], cols_s[o], vals_s[o]);
    }

    // 3. per-order: encoders -> K-hop propagation (modalities fused on 512 cols)
    for (int o = 0; o < 2; o++) {
        // h_rna -> xk_a[:, 0:256], h_atac -> xk_a[:, 256:512]
        {
            dim3 g(cdiv(HID, 64), cdiv(NC, 64));
            gemm_f32<64, 64, 16, 4, 4, false><<<g, 256, 0, stream>>>(
                X_rna, D_RNA, Wi_rna + (size_t)o * D_RNA * HID, HID,
                bi_rna + o * HID, xk_a, 512, NC, HID, D_RNA);
            gemm_f32<64, 64, 16, 4, 4, false><<<g, 256, 0, stream>>>(
                X_atac, D_ATAC, Wi_atac + (size_t)o * D_ATAC * HID, HID,
                bi_atac + o * HID, xk_a + 256, 512, NC, HID, D_ATAC);
        }
        init_acc_kernel<<<NC, 512, 0, stream>>>(xk_a, Zrna, Zatac, fw_soft, o);
        float* src = xk_a;
        float* dst = xk_b;
        for (int k = 1; k <= KHOP; k++) {
            spmm_acc_kernel<<<NC, 512, 0, stream>>>(
                rstart[o], cols_s[o], vals_s[o], src, dst, Zrna, Zatac, fw_soft, o, k);
            float* t = src; src = dst; dst = t;
        }
    }

    // 4. Wo GEMMs -> z_rna, z_atac
    {
        dim3 g(cdiv(HID, 64), cdiv(NC, 64));
        gemm_f32<64, 64, 16, 4, 4, false><<<g, 256, 0, stream>>>(
            Zrna, 512, Wo_rna, HID, bo_rna, o_z_rna, HID, NC, HID, 512);
        gemm_f32<64, 64, 16, 4, 4, false><<<g, 256, 0, stream>>>(
            Zatac, 512, Wo_atac, HID, bo_atac, o_z_atac, HID, NC, HID, 512);
    }

    // 5. attention fusion -> z, weight
    attention_kernel<<<NC, 256, 0, stream>>>(o_z_rna, o_z_atac, Wa, ba, o_z, o_weight);

    // 6. decoder hidden layers (relu)
    {
        dim3 g(cdiv(HID, 64), cdiv(NC, 64));
        gemm_f32<64, 64, 16, 4, 4, true><<<g, 256, 0, stream>>>(
            o_z, HID, Wd1_rna, HID, bd1_rna, d1_rna, HID, NC, HID, HID);
        gemm_f32<64, 64, 16, 4, 4, true><<<g, 256, 0, stream>>>(
            o_z, HID, Wd1_atac, HID, bd1_atac, d1_atac, HID, NC, HID, HID);
    }

    // 7. decoder output layers (overwrites the scratch region last)
    {
        dim3 g1(cdiv(D_RNA, 128), cdiv(NC, 128));
        gemm_f32<128, 128, 8, 8, 8, false><<<g1, 256, 0, stream>>>(
            d1_rna, HID, Wd2_rna, D_RNA, bd2_rna, o_rna_rec, D_RNA, NC, D_RNA, HID);
        dim3 g2(cdiv(D_ATAC, 128), cdiv(NC, 128));
        gemm_f32<128, 128, 8, 8, 8, false><<<g2, 256, 0, stream>>>(
            d1_atac, HID, Wd2_atac, D_ATAC, bd2_atac, o_atac_rec, D_ATAC, NC, D_ATAC, HID);
    }
}